// Round 5
// baseline (352.065 us; speedup 1.0000x reference)
//
#include <hip/hip_runtime.h>
#include <stdint.h>

#define T_ 128

typedef int v4i __attribute__((ext_vector_type(4)));

// ---------------------------------------------------------------------------
// prep 1: static B-fragments for mfma_i32_16x16x64_i8, biased i8 (byte-128).
// Fragment mf = (tau*5 + kappa)*2 + h. Lane l holds n = l&15,
// k-slots kin = (l>>4)*16 + 4r + b — identical slot->k map as scan's A, so
// any HW k-permutation cancels in the dot.
__global__ void prep_bfrag(const int* __restrict__ sc, uint4* __restrict__ bf) {
  int gid = blockIdx.x * 256 + threadIdx.x;
  if (gid >= 160 * 64) return;
  int mf = gid >> 6, l = gid & 63;
  int tau = mf / 10, rem = mf % 10;
  int kap = rem >> 1, h = rem & 1;
  int j = 16 * tau + (l & 15);
  int kinb = (l >> 4) * 16;
  unsigned wout[4];
#pragma unroll
  for (int r = 0; r < 4; ++r) {
    unsigned wrd = 0;
#pragma unroll
    for (int be = 0; be < 4; ++be) {
      int kin = kinb + 4 * r + be;
      int col = (kap == 0) ? kin : 64 + ((kap - 1) << 6) + kin;
      unsigned c = (unsigned)sc[j * 320 + col];
      unsigned byte = (h ? (c >> 8) : c) & 0xFFu;
      byte = (byte - 128u) & 0xFFu;
      wrd |= byte << (8 * be);
    }
    wout[r] = wrd;
  }
  bf[gid] = make_uint4(wout[0], wout[1], wout[2], wout[3]);
}

// prep 2: window bits packed to u64 per (b,t)
__global__ void prep_wbits(const int* __restrict__ bits,
                           unsigned long long* __restrict__ wb) {
  int gid = blockIdx.x * 256 + threadIdx.x;
  int wv = gid >> 6, lane = gid & 63;
  unsigned long long m = __ballot(bits[gid] != 0);
  if (lane == 0) wb[wv] = m;
}

// prep 3: bitpack (state_mem >= 0.5) -> 2 MiB table (L2-resident for scan)
__global__ void prep_bitpack(const float* __restrict__ sm,
                             unsigned long long* __restrict__ packed) {
  int base = blockIdx.x * (256 * 32) + threadIdx.x;
  int lane = threadIdx.x & 63;
#pragma unroll 1
  for (int it = 0; it < 32; ++it) {
    int idx = base + it * 256;
    float v = sm[idx];
    unsigned long long m = __ballot(v >= 0.5f);
    if (lane == 0) packed[idx >> 6] = m;
  }
}

// ---------------------------------------------------------------------------
// per-lane expand of a 16-bit slice into an i8 {0,1} A-fragment
static __device__ __forceinline__ v4i expand16(unsigned b16) {
  v4i a;
#pragma unroll
  for (int r = 0; r < 4; ++r) {
    unsigned nib = (b16 >> (4 * r)) & 0xFu;
    a[r] = (int)((nib * 0x00204081u) & 0x01010101u);
  }
  return a;
}

// scan + heads: 1 block per batch row, 8 waves of 64. Wave w owns N-tiles
// {2w,2w+1} = j in [32w,32w+32). launch_bounds(512,2): 2 waves/EU min ->
// ~256-VGPR budget so the 20 B-fragments live in true VGPRs (no accvgpr
// moves). NB/corr on the scalar pipe via readfirstlane.
__global__ __launch_bounds__(512, 2) void scan_heads(
    const uint4* __restrict__ bfrag,
    const unsigned long long* __restrict__ wbits,
    const unsigned* __restrict__ packed32,
    const int* __restrict__ head_conn,
    const int* __restrict__ head_coeffs,
    const float* __restrict__ head_mem,
    float* __restrict__ out) {
  __shared__ __align__(16) unsigned msh[2][8];
  const int tid = threadIdx.x;
  const int b = blockIdx.x;
  const int w = tid >> 6, l = tid & 63;
  const int qq = (l >> 4) & 3;          // 16-bit slice index within 64-bit chunk
  const int sh = 16 * (qq & 1);         // shift within a u32 state word
  const int wi = qq >> 1;               // u32 word parity within a u64 chunk

  // one-time: 20 static B-fragments (tiles 2w,2w+1) into registers
  v4i bf[2][5][2];
#pragma unroll
  for (int i = 0; i < 2; ++i)
#pragma unroll
    for (int k = 0; k < 5; ++k)
#pragma unroll
      for (int h = 0; h < 2; ++h) {
        int mf = ((2 * w + i) * 5 + k) * 2 + h;
        bf[i][k][h] = __builtin_bit_cast(v4i, bfrag[mf * 64 + l]);
      }

  unsigned words[8];
#pragma unroll
  for (int i = 0; i < 8; ++i) words[i] = 0u;  // state0 = 0
  unsigned long long wcur = wbits[b * 128];

  // pre-init accumulators with the t=0 window (k=0) contribution
  v4i acc[2][2];
  {
    v4i aw = expand16((unsigned)((wcur >> (16 * qq)) & 0xFFFFu));
    v4i z = (v4i){0, 0, 0, 0};
#pragma unroll
    for (int i = 0; i < 2; ++i)
#pragma unroll
      for (int h = 0; h < 2; ++h)
        acc[i][h] = __builtin_amdgcn_mfma_i32_16x16x64_i8(aw, bf[i][0][h], z, 0, 0, 0);
  }

#pragma unroll 1
  for (int t = 0; t < T_; ++t) {
    // NB on the scalar pipe: state words are wave-uniform
    unsigned NB = (unsigned)__popcll(wcur);
#pragma unroll
    for (int i = 0; i < 8; ++i) {
      unsigned sw = (unsigned)__builtin_amdgcn_readfirstlane((int)words[i]);
      NB += (unsigned)__popc((int)sw);
    }

    // state-chunk A fragments and 16 MFMAs (k-chunks 1..4)
#pragma unroll
    for (int c = 0; c < 4; ++c) {
      v4i a = expand16((words[2 * c + wi] >> sh) & 0xFFFFu);
      acc[0][0] = __builtin_amdgcn_mfma_i32_16x16x64_i8(a, bf[0][c + 1][0], acc[0][0], 0, 0, 0);
      acc[0][1] = __builtin_amdgcn_mfma_i32_16x16x64_i8(a, bf[0][c + 1][1], acc[0][1], 0, 0, 0);
      acc[1][0] = __builtin_amdgcn_mfma_i32_16x16x64_i8(a, bf[1][c + 1][0], acc[1][0], 0, 0, 0);
      acc[1][1] = __builtin_amdgcn_mfma_i32_16x16x64_i8(a, bf[1][c + 1][1], acc[1][1], 0, 0, 0);
    }

    int tn = (t + 1 < T_) ? t + 1 : t;
    unsigned long long wnext = wbits[b * 128 + tn];

    // epilogue: addr for j = 32w + l (lanes 0..31), selected in-register
    unsigned corr = (NB * 32896u) & 0xFFFFu;  // 128*257 bias fixup (scalar)
    unsigned lo = (unsigned)((l & 16) ? acc[1][0][0] : acc[0][0][0]);
    unsigned hi = (unsigned)((l & 16) ? acc[1][1][0] : acc[0][1][0]);
    unsigned ad = (lo + (hi << 8) + corr) & 0xFFFFu;

    // self-gather: 32 lanes/wave, 256 requests/block total
    unsigned bitv = 0;
    if (l < 32) {
      unsigned word = packed32[((size_t)(32 * w + l) << 11) + (ad >> 5)];
      bitv = (word >> (ad & 31)) & 1u;
    }
    unsigned long long mq = __ballot(bitv != 0u);
    if (l == 0) msh[t & 1][w] = (unsigned)mq;

    // fill gather latency: next step's window-chunk MFMAs into fresh accs
    {
      v4i aw = expand16((unsigned)((wnext >> (16 * qq)) & 0xFFFFu));
      v4i z = (v4i){0, 0, 0, 0};
#pragma unroll
      for (int i = 0; i < 2; ++i)
#pragma unroll
        for (int h = 0; h < 2; ++h)
          acc[i][h] = __builtin_amdgcn_mfma_i32_16x16x64_i8(aw, bf[i][0][h], z, 0, 0, 0);
    }

    __syncthreads();

    uint4 u0 = *((const uint4*)&msh[t & 1][0]);
    uint4 u1 = *((const uint4*)&msh[t & 1][4]);
    words[0] = u0.x; words[1] = u0.y; words[2] = u0.z; words[3] = u0.w;
    words[4] = u1.x; words[5] = u1.y; words[6] = u1.z; words[7] = u1.w;
    wcur = wnext;
  }

  // ---- heads (wave 0): only the selected head per batch row
  if (w == 0) {
    int h = (int)((((wcur >> 61) & 1) << 2) | (((wcur >> 62) & 1) << 1) |
                  ((wcur >> 63) & 1));
    int ho = h * 64 + l;
    const int4* cn4 = (const int4*)(head_conn + ho * 8);
    const int4* cf4 = (const int4*)(head_coeffs + ho * 8);
    int4 cna = cn4[0], cnb = cn4[1];
    int4 cfa = cf4[0], cfb = cf4[1];
    int cns[8] = {cna.x, cna.y, cna.z, cna.w, cnb.x, cnb.y, cnb.z, cnb.w};
    int cfs[8] = {cfa.x, cfa.y, cfa.z, cfa.w, cfb.x, cfb.y, cfb.z, cfb.w};
    unsigned addr = 0;
#pragma unroll
    for (int k = 0; k < 8; ++k) {
      unsigned bit = (words[cns[k] >> 5] >> (cns[k] & 31)) & 1u;
      addr += bit * (unsigned)cfs[k];
    }
    addr &= 0xFFFFu;
    out[b * 64 + l] = head_mem[((size_t)ho << 16) + addr];
  }
}

extern "C" void kernel_launch(void* const* d_in, const int* in_sizes, int n_in,
                              void* d_out, int out_size, void* d_ws, size_t ws_size,
                              hipStream_t stream) {
  const int*   bits         = (const int*)d_in[0];
  const int*   state_coeffs = (const int*)d_in[1];
  const float* state_mem    = (const float*)d_in[2];
  const int*   head_conn    = (const int*)d_in[3];
  const int*   head_coeffs  = (const int*)d_in[4];
  const float* head_mem     = (const float*)d_in[5];
  float* out = (float*)d_out;

  char* ws = (char*)d_ws;
  uint4*              bfrag  = (uint4*)ws;                             // 160 KiB
  unsigned long long* wbits  = (unsigned long long*)(ws + (160 << 10)); // 128 KiB
  unsigned*           packed = (unsigned*)(ws + (288 << 10));          // 2 MiB

  prep_bfrag<<<40, 256, 0, stream>>>(state_coeffs, bfrag);
  prep_wbits<<<4096, 256, 0, stream>>>(bits, wbits);
  prep_bitpack<<<2048, 256, 0, stream>>>(state_mem, (unsigned long long*)packed);
  scan_heads<<<128, 512, 0, stream>>>(bfrag, wbits, packed,
                                      head_conn, head_coeffs, head_mem, out);
}